// Round 2
// baseline (2254.023 us; speedup 1.0000x reference)
//
#include <hip/hip_runtime.h>
#include <stdint.h>

// ---------------------------------------------------------------------------
// KeypointMatchingModel: B=8, N=128, C_IN=C_OUT=512, H_MLP=128, STEPS=10,
// DEG=16, E=16384, NN=1024. Rows stacked: s-side 0..1023, t-side 1024..2047.
//
// Graph aggregation converted to dense batched GEMM:
//   out1 = D_dst^-1 A (xW1),  out2 = D_src^-1 A^T (xW2),  A[d][s]=edge count.
// GNN(s & t batched, shared weights):
//   Y = XH[:, :512] @ [W1|W2|Wr]  (2048x1536)
//   agg = M1@Y1 + M2@Y2 (16 batched 128x512x128)
//   h = LN(relu(Y[:,1024:]+br+agg)); XH[:,512:1024]=h
//   O = XH @ Fw + Fb  (2048x512x1024)
// RNG: jax threefry, PARTITIONABLE counter scheme:
//   counts = (hi,lo) of 64-bit flat index = (0, i); bits = o0 ^ o1  (jax
//   _threefry_random_bits_partitionable returns bits1 ^ bits2 for width<64).
//   [R1 post-mortem: o0 alone failed with absmax 0.83 on output 1 only.]
//   Fallback if still wrong: legacy scheme = pairs (i, 262144+i) -> (o0,o1).
// ---------------------------------------------------------------------------

__host__ __device__ inline void tf2x32(uint32_t k0, uint32_t k1, uint32_t x0,
                                       uint32_t x1, uint32_t& o0, uint32_t& o1) {
  uint32_t ks0 = k0, ks1 = k1, ks2 = 0x1BD11BDAu ^ k0 ^ k1;
  x0 += ks0; x1 += ks1;
#define TF_R(r) { x0 += x1; x1 = (x1 << r) | (x1 >> (32 - r)); x1 ^= x0; }
  TF_R(13) TF_R(15) TF_R(26) TF_R(6)   x0 += ks1; x1 += ks2 + 1u;
  TF_R(17) TF_R(29) TF_R(16) TF_R(24)  x0 += ks2; x1 += ks0 + 2u;
  TF_R(13) TF_R(15) TF_R(26) TF_R(6)   x0 += ks0; x1 += ks1 + 3u;
  TF_R(17) TF_R(29) TF_R(16) TF_R(24)  x0 += ks1; x1 += ks2 + 4u;
  TF_R(13) TF_R(15) TF_R(26) TF_R(6)   x0 += ks2; x1 += ks0 + 5u;
#undef TF_R
  o0 = x0; o1 = x1;
}

__device__ inline float erfinv_f(float x) {  // XLA ErfInv32 (Giles)
  float w = -log1pf(-x * x);
  float p;
  if (w < 5.0f) {
    w = w - 2.5f;
    p = 2.81022636e-08f;
    p = fmaf(p, w, 3.43273939e-07f);
    p = fmaf(p, w, -3.5233877e-06f);
    p = fmaf(p, w, -4.39150654e-06f);
    p = fmaf(p, w, 0.00021858087f);
    p = fmaf(p, w, -0.00125372503f);
    p = fmaf(p, w, -0.00417768164f);
    p = fmaf(p, w, 0.246640727f);
    p = fmaf(p, w, 1.50140941f);
  } else {
    w = sqrtf(w) - 3.0f;
    p = -0.000200214257f;
    p = fmaf(p, w, 0.000100950558f);
    p = fmaf(p, w, 0.00134934322f);
    p = fmaf(p, w, -0.00367342844f);
    p = fmaf(p, w, 0.00573950773f);
    p = fmaf(p, w, -0.0076224613f);
    p = fmaf(p, w, 0.00943887047f);
    p = fmaf(p, w, 1.00167406f);
    p = fmaf(p, w, 2.83297682f);
  }
  return p * x;
}

__device__ inline float bits_to_normal(uint32_t bits) {
  uint32_t fb = (bits >> 9) | 0x3f800000u;
  float f = __uint_as_float(fb) - 1.0f;          // [0,1)
  float u = f * 2.0f + (-0.99999994f);           // lo=nextafter(-1,0), hi-lo==2.0f
  u = fmaxf(-0.99999994f, u);
  return 1.41421356f * erfinv_f(u);              // sqrt(2) in f32
}

// R_s generation: partitionable threefry. i in [0, 524288), bits = o0^o1 of
// block(key, hi=0, lo=i).
__global__ __launch_bounds__(256) void rng_kernel(float* __restrict__ XH,
                                                  uint32_t k0, uint32_t k1) {
  uint32_t i = blockIdx.x * 256 + threadIdx.x;   // 524288 threads
  uint32_t o0, o1;
  tf2x32(k0, k1, 0u, i, o0, o1);
  float val = bits_to_normal(o0 ^ o1);
  uint32_t row = i >> 9, col = i & 511;          // (8*128) x 512
  XH[row * 1024 + col] = val;                    // s-side rows, left half
}

// Adjacency build
__global__ __launch_bounds__(256) void count_kernel(const int* __restrict__ ei_s,
                                                    const int* __restrict__ ei_t,
                                                    int* __restrict__ Acnt,
                                                    int* __restrict__ degd,
                                                    int* __restrict__ degs) {
  int e = blockIdx.x * 256 + threadIdx.x;        // 32768
  int side = e >> 14, idx = e & 16383;
  const int* ei = side ? ei_t : ei_s;
  int src = ei[idx], dst = ei[16384 + idx];
  int g = (dst >> 7) + side * 8;                 // 0..15
  int dl = dst & 127, sl = src & 127;
  atomicAdd(&Acnt[(g * 128 + dl) * 128 + sl], 1);
  atomicAdd(&degd[g * 128 + dl], 1);
  atomicAdd(&degs[g * 128 + sl], 1);
}

__global__ __launch_bounds__(256) void norm_adj_kernel(const int* __restrict__ Acnt,
                                                       const int* __restrict__ degd,
                                                       const int* __restrict__ degs,
                                                       float* __restrict__ M1,
                                                       float* __restrict__ M2) {
  int idx = blockIdx.x * 256 + threadIdx.x;      // 16*128*128
  int g = idx >> 14, d = (idx >> 7) & 127, s = idx & 127;
  float a = (float)Acnt[idx];
  M1[idx] = a / (float)max(degd[g * 128 + d], 1);
  M2[(g * 128 + s) * 128 + d] = a / (float)max(degs[g * 128 + s], 1);
}

__global__ __launch_bounds__(256) void pack_kernel(const float* __restrict__ W1,
                                                   const float* __restrict__ W2,
                                                   const float* __restrict__ Wr,
                                                   float* __restrict__ Wcat) {
  int idx = blockIdx.x * 256 + threadIdx.x;      // 512 * 384 float4s
  int k = idx / 384, j4 = (idx % 384) * 4;
  float4 v;
  if (j4 < 512)       v = *(const float4*)&W1[k * 512 + j4];
  else if (j4 < 1024) v = *(const float4*)&W2[k * 512 + j4 - 512];
  else                v = *(const float4*)&Wr[k * 512 + j4 - 1024];
  *(float4*)&Wcat[k * 1536 + j4] = v;
}

__global__ __launch_bounds__(256) void copyx_kernel(const float* __restrict__ xs,
                                                    const float* __restrict__ xt,
                                                    float* __restrict__ XH) {
  int idx = blockIdx.x * 256 + threadIdx.x;      // 2048 rows * 128 float4s
  int row = idx >> 7, c4 = (idx & 127) << 2;
  const float* src = (row < 1024) ? (xs + row * 512 + c4)
                                  : (xt + (row - 1024) * 512 + c4);
  *(float4*)&XH[row * 1024 + c4] = *(const float4*)src;
}

// ---------------- generic fp32 tiled GEMM, 64x64x16, 256 thr, 4x4/thr -------
template <int TRANSA, int TRANSB>
__global__ __launch_bounds__(256) void gemm_kernel(
    int M, int N, int K,
    const float* __restrict__ A, int lda, int strideA,
    const float* __restrict__ B, int ldb, int strideB,
    float* __restrict__ C, int ldc, int strideC,
    const float* __restrict__ bias, int beta) {
  int batch = blockIdx.z;
  A += (size_t)batch * strideA;
  B += (size_t)batch * strideB;
  C += (size_t)batch * strideC;
  int m0 = blockIdx.y * 64, n0 = blockIdx.x * 64;
  __shared__ float As[16][64];
  __shared__ float Bs[16][64];
  int tid = threadIdx.x;
  int tx = tid & 15, ty = tid >> 4;
  float acc[4][4] = {};
  for (int k0 = 0; k0 < K; k0 += 16) {
    if (!TRANSA) {
      int m_l = tid & 63, k_l = (tid >> 6) << 2;
      float4 av = *(const float4*)&A[(m0 + m_l) * lda + k0 + k_l];
      As[k_l + 0][m_l] = av.x; As[k_l + 1][m_l] = av.y;
      As[k_l + 2][m_l] = av.z; As[k_l + 3][m_l] = av.w;
    } else {  // A is KxM
      int k_l = tid >> 4, m_l = (tid & 15) << 2;
      float4 av = *(const float4*)&A[(k0 + k_l) * lda + m0 + m_l];
      *(float4*)&As[k_l][m_l] = av;
    }
    if (!TRANSB) {
      int k_l = tid >> 4, n_l = (tid & 15) << 2;
      float4 bv = *(const float4*)&B[(k0 + k_l) * ldb + n0 + n_l];
      *(float4*)&Bs[k_l][n_l] = bv;
    } else {  // B is NxK
      int n_l = tid >> 2, k_l = (tid & 3) << 2;
      float4 bv = *(const float4*)&B[(n0 + n_l) * ldb + k0 + k_l];
      Bs[k_l + 0][n_l] = bv.x; Bs[k_l + 1][n_l] = bv.y;
      Bs[k_l + 2][n_l] = bv.z; Bs[k_l + 3][n_l] = bv.w;
    }
    __syncthreads();
#pragma unroll
    for (int kk = 0; kk < 16; ++kk) {
      float4 a4 = *(const float4*)&As[kk][ty << 2];
      float4 b4 = *(const float4*)&Bs[kk][tx << 2];
      float av[4] = {a4.x, a4.y, a4.z, a4.w};
      float bv[4] = {b4.x, b4.y, b4.z, b4.w};
#pragma unroll
      for (int i = 0; i < 4; ++i)
#pragma unroll
        for (int j = 0; j < 4; ++j) acc[i][j] = fmaf(av[i], bv[j], acc[i][j]);
    }
    __syncthreads();
  }
#pragma unroll
  for (int i = 0; i < 4; ++i) {
    int m = m0 + (ty << 2) + i;
    float4* cp = (float4*)&C[m * ldc + n0 + (tx << 2)];
    float4 v = {acc[i][0], acc[i][1], acc[i][2], acc[i][3]};
    if (bias) {
      float4 bb = *(const float4*)&bias[n0 + (tx << 2)];
      v.x += bb.x; v.y += bb.y; v.z += bb.z; v.w += bb.w;
    }
    if (beta) {
      float4 c = *cp;
      v.x += c.x; v.y += c.y; v.z += c.z; v.w += c.w;
    }
    *cp = v;
  }
}

// relu + LayerNorm over 512, write h into XH right half
__global__ __launch_bounds__(256) void relu_ln_kernel(
    const float* __restrict__ Y, const float* __restrict__ agg,
    const float* __restrict__ rb, const float* __restrict__ gam,
    const float* __restrict__ bet, float* __restrict__ XH) {
  int row = blockIdx.x;
  int tid = threadIdx.x;
  int c0 = tid, c1 = tid + 256;
  float v0 = fmaxf(Y[row * 1536 + 1024 + c0] + rb[c0] + agg[row * 512 + c0], 0.f);
  float v1 = fmaxf(Y[row * 1536 + 1024 + c1] + rb[c1] + agg[row * 512 + c1], 0.f);
  float s = v0 + v1, s2 = v0 * v0 + v1 * v1;
#pragma unroll
  for (int off = 32; off > 0; off >>= 1) {
    s += __shfl_down(s, off);
    s2 += __shfl_down(s2, off);
  }
  __shared__ float red[2][4];
  int wid = tid >> 6, lane = tid & 63;
  if (lane == 0) { red[0][wid] = s; red[1][wid] = s2; }
  __syncthreads();
  s = red[0][0] + red[0][1] + red[0][2] + red[0][3];
  s2 = red[1][0] + red[1][1] + red[1][2] + red[1][3];
  float mu = s * (1.f / 512.f);
  float var = s2 * (1.f / 512.f) - mu * mu;
  float inv = 1.f / sqrtf(var + 1e-5f);
  XH[row * 1024 + 512 + c0] = (v0 - mu) * inv * gam[c0] + bet[c0];
  XH[row * 1024 + 512 + c1] = (v1 - mu) * inv * gam[c1] + bet[c1];
}

__global__ __launch_bounds__(64) void softmax_kernel(const float* __restrict__ SH,
                                                     float* __restrict__ S,
                                                     float* __restrict__ out2) {
  int row = blockIdx.x;      // 1024 = b*128+s
  int lane = threadIdx.x;    // 64
  float a = SH[row * 128 + lane];
  float b = SH[row * 128 + 64 + lane];
  float m = fmaxf(a, b);
#pragma unroll
  for (int off = 32; off > 0; off >>= 1) m = fmaxf(m, __shfl_xor(m, off));
  float e0 = expf(a - m), e1 = expf(b - m);
  float ssum = e0 + e1;
#pragma unroll
  for (int off = 32; off > 0; off >>= 1) ssum += __shfl_xor(ssum, off);
  float r0 = e0 / ssum, r1 = e1 / ssum;
  S[row * 128 + lane] = r0;
  S[row * 128 + 64 + lane] = r1;
  if (out2) {
    out2[row * 128 + lane] = r0;
    out2[row * 128 + 64 + lane] = r1;
  }
}

// S_hat[b,s,t] += sum_h relu(P_s[b,s,h] - P_t[b,t,h] + b1[h]) * w2[h] + b2
__global__ __launch_bounds__(128) void dist_kernel(const float* __restrict__ P,
                                                   const float* __restrict__ b1,
                                                   const float* __restrict__ w2,
                                                   const float* __restrict__ b2,
                                                   float* __restrict__ SH) {
  int bs = blockIdx.x;       // b*128+s
  int b = bs >> 7;
  int t = threadIdx.x;       // 128
  __shared__ float arow[128], w2s[128];
  arow[t] = P[bs * 128 + t] + b1[t];
  w2s[t] = w2[t];
  __syncthreads();
  const float* pt = &P[(1024 + b * 128 + t) * 128];
  float acc = 0.f;
#pragma unroll 8
  for (int h4 = 0; h4 < 128; h4 += 4) {
    float4 a = *(const float4*)&arow[h4];
    float4 w = *(const float4*)&w2s[h4];
    float4 p = *(const float4*)&pt[h4];
    acc += fmaxf(a.x - p.x, 0.f) * w.x + fmaxf(a.y - p.y, 0.f) * w.y +
           fmaxf(a.z - p.z, 0.f) * w.z + fmaxf(a.w - p.w, 0.f) * w.w;
  }
  SH[bs * 128 + t] += acc + b2[0];
}

// ---------------------------------------------------------------------------
extern "C" void kernel_launch(void* const* d_in, const int* in_sizes, int n_in,
                              void* d_out, int out_size, void* d_ws, size_t ws_size,
                              hipStream_t stream) {
  const float* x_s = (const float*)d_in[0];
  const int* ei_s = (const int*)d_in[1];
  const float* x_t = (const float*)d_in[4];
  const int* ei_t = (const int*)d_in[5];
  const float* e_lin1 = (const float*)d_in[8];
  const float* e_lin2 = (const float*)d_in[9];
  const float* e_rw = (const float*)d_in[10];
  const float* e_rb = (const float*)d_in[11];
  const float* e_g = (const float*)d_in[12];
  const float* e_b = (const float*)d_in[13];
  const float* e_fw = (const float*)d_in[14];
  const float* e_fb = (const float*)d_in[15];
  const float* c_lin1 = (const float*)d_in[16];
  const float* c_lin2 = (const float*)d_in[17];
  const float* c_rw = (const float*)d_in[18];
  const float* c_rb = (const float*)d_in[19];
  const float* c_g = (const float*)d_in[20];
  const float* c_b = (const float*)d_in[21];
  const float* c_fw = (const float*)d_in[22];
  const float* c_fb = (const float*)d_in[23];
  const float* m_w1 = (const float*)d_in[24];
  const float* m_b1 = (const float*)d_in[25];
  const float* m_w2 = (const float*)d_in[26];
  const float* m_b2 = (const float*)d_in[27];
  float* out = (float*)d_out;
  float* ws = (float*)d_ws;

  // workspace layout (floats)
  float* Wcat_e = ws;                   // 786432
  float* Wcat_c = ws + 786432;          // 786432
  float* M1 = ws + 1572864;             // 262144  [16][128][128]
  float* M2 = ws + 1835008;             // 262144
  float* XH = ws + 2097152;             // 2097152 [2048][1024]
  float* Y  = ws + 4194304;             // 3145728 [2048][1536]
  float* AGG = ws + 7340032;            // 1048576 [2048][512]
  float* O  = ws + 8388608;             // 1048576 [2048][512]
  float* P  = ws + 9437184;             // 262144  [2048][128]
  float* SH = ws + 9699328;             // 131072  [8][128][128]
  float* S  = ws + 9830400;             // 131072
  int* Acnt = (int*)(ws + 9961472);     // 262144 ints
  int* degd = (int*)(ws + 10223616);    // 2048
  int* degs = (int*)(ws + 10225664);    // 2048  (total 10227712 floats ~ 39MB)

  hipMemsetAsync(Acnt, 0, (262144 + 2048 + 2048) * sizeof(int), stream);
  count_kernel<<<128, 256, 0, stream>>>(ei_s, ei_t, Acnt, degd, degs);
  norm_adj_kernel<<<1024, 256, 0, stream>>>(Acnt, degd, degs, M1, M2);
  pack_kernel<<<768, 256, 0, stream>>>(e_lin1, e_lin2, e_rw, Wcat_e);
  pack_kernel<<<768, 256, 0, stream>>>(c_lin1, c_lin2, c_rw, Wcat_c);
  copyx_kernel<<<1024, 256, 0, stream>>>(x_s, x_t, XH);

  auto gnn = [&](const float* Wcat, const float* rb, const float* g,
                 const float* bb, const float* Fw, const float* Fb) {
    // Y = XH[:, :512] @ Wcat
    gemm_kernel<0, 0><<<dim3(24, 32, 1), 256, 0, stream>>>(
        2048, 1536, 512, XH, 1024, 0, Wcat, 1536, 0, Y, 1536, 0, nullptr, 0);
    // agg = M1@Y1 ; agg += M2@Y2   (16 batched)
    gemm_kernel<0, 0><<<dim3(8, 2, 16), 256, 0, stream>>>(
        128, 512, 128, M1, 128, 16384, Y, 1536, 128 * 1536, AGG, 512, 128 * 512,
        nullptr, 0);
    gemm_kernel<0, 0><<<dim3(8, 2, 16), 256, 0, stream>>>(
        128, 512, 128, M2, 128, 16384, Y + 512, 1536, 128 * 1536, AGG, 512,
        128 * 512, nullptr, 1);
    relu_ln_kernel<<<2048, 256, 0, stream>>>(Y, AGG, rb, g, bb, XH);
    // O = XH @ Fw + Fb
    gemm_kernel<0, 0><<<dim3(8, 32, 1), 256, 0, stream>>>(
        2048, 512, 1024, XH, 1024, 0, Fw, 512, 0, O, 512, 0, Fb, 0);
  };

  // ---- embedding GNN (s&t batched) -> O holds Hs (rows 0..1023), Ht (1024..2047)
  gnn(Wcat_e, e_rb, e_g, e_b, e_fw, e_fb);
  // S_hat[b] = Hs[b] @ Ht[b]^T   (8 batched, transB)
  gemm_kernel<0, 1><<<dim3(2, 2, 8), 256, 0, stream>>>(
      128, 128, 512, O, 512, 128 * 512, O + 1024 * 512, 512, 128 * 512, SH, 128,
      128 * 128, nullptr, 0);

  for (int t = 0; t < 10; ++t) {
    softmax_kernel<<<1024, 64, 0, stream>>>(SH, S, (t == 0) ? out : nullptr);
    uint32_t fk0, fk1;
    tf2x32(0u, 42u, 0u, (uint32_t)t, fk0, fk1);  // fold_in(key(42), t)
    rng_kernel<<<2048, 256, 0, stream>>>(XH, fk0, fk1);  // R_s -> XH s-rows left
    // R_t[b] = S[b]^T @ R_s[b]  -> XH t-rows left  (8 batched, transA)
    gemm_kernel<1, 0><<<dim3(8, 2, 8), 256, 0, stream>>>(
        128, 512, 128, S, 128, 128 * 128, XH, 1024, 128 * 1024,
        XH + 1024 * 1024, 1024, 128 * 1024, nullptr, 0);
    gnn(Wcat_c, c_rb, c_g, c_b, c_fw, c_fb);
    // P = O @ m_w1 + m_b1  (both halves biased; dist re-adds b1 to the s row)
    gemm_kernel<0, 0><<<dim3(2, 32, 1), 256, 0, stream>>>(
        2048, 128, 512, O, 512, 0, m_w1, 128, 0, P, 128, 0, m_b1, 0);
    dist_kernel<<<1024, 128, 0, stream>>>(P, m_b1, m_w2, m_b2, SH);
  }
  softmax_kernel<<<1024, 64, 0, stream>>>(SH, S, out + 131072);
}

// Round 3
// 1474.772 us; speedup vs baseline: 1.5284x; 1.5284x over previous
//
#include <hip/hip_runtime.h>
#include <stdint.h>

// ---------------------------------------------------------------------------
// KeypointMatchingModel: B=8, N=128, C_IN=C_OUT=512, H_MLP=128, STEPS=10.
// R2 baseline (all-fp32 vector): 2254 us, MfmaUtil=0, big GEMM at 41 TF.
// R3: split-bf16 MFMA (Ah+Al)(Bh+Bl) ~= AhBh+AhBl+AlBh (3 MFMA, ~16-bit
// mantissa, logit err ~1e-4) for the two dominant GEMMs:
//   G1: Y = XH[:,:512] @ Wcat   (2048x1536x512)
//   G2: O = XH @ Fw + Fb        (2048x512x1024)
// XH kept as bf16 hi/lo planes [2048][1024], written directly by producers
// (copyx, rng, relu_ln, R_t gemm epilogue). Weights pre-transposed to [N][K]
// bf16 hi/lo so A and B tiles stage identically (128B rows, XOR swizzle,
// ds_read_b128 fragments). Small batched GEMMs (agg, R_t, SH, P) stay fp32.
// RNG: jax threefry partitionable, bits = o0^o1 of block(key, 0, i). VERIFIED.
// ---------------------------------------------------------------------------

typedef unsigned short u16;
typedef unsigned int u32;
typedef __attribute__((ext_vector_type(8))) short short8;
typedef __attribute__((ext_vector_type(4))) float f32x4;

__device__ inline u16 f2bf(float x) {
  u32 u = __float_as_uint(x);
  u32 r = (u + 0x7fffu + ((u >> 16) & 1u)) >> 16;  // round-nearest-even
  return (u16)r;
}
__device__ inline float bf2f(u16 h) { return __uint_as_float(((u32)h) << 16); }
__device__ inline void split2(float x, u16& h, u16& l) {
  h = f2bf(x);
  l = f2bf(x - bf2f(h));
}

__host__ __device__ inline void tf2x32(uint32_t k0, uint32_t k1, uint32_t x0,
                                       uint32_t x1, uint32_t& o0, uint32_t& o1) {
  uint32_t ks0 = k0, ks1 = k1, ks2 = 0x1BD11BDAu ^ k0 ^ k1;
  x0 += ks0; x1 += ks1;
#define TF_R(r) { x0 += x1; x1 = (x1 << r) | (x1 >> (32 - r)); x1 ^= x0; }
  TF_R(13) TF_R(15) TF_R(26) TF_R(6)   x0 += ks1; x1 += ks2 + 1u;
  TF_R(17) TF_R(29) TF_R(16) TF_R(24)  x0 += ks2; x1 += ks0 + 2u;
  TF_R(13) TF_R(15) TF_R(26) TF_R(6)   x0 += ks0; x1 += ks1 + 3u;
  TF_R(17) TF_R(29) TF_R(16) TF_R(24)  x0 += ks1; x1 += ks2 + 4u;
  TF_R(13) TF_R(15) TF_R(26) TF_R(6)   x0 += ks2; x1 += ks0 + 5u;
#undef TF_R
  o0 = x0; o1 = x1;
}

__device__ inline float erfinv_f(float x) {  // XLA ErfInv32 (Giles)
  float w = -log1pf(-x * x);
  float p;
  if (w < 5.0f) {
    w = w - 2.5f;
    p = 2.81022636e-08f;
    p = fmaf(p, w, 3.43273939e-07f);
    p = fmaf(p, w, -3.5233877e-06f);
    p = fmaf(p, w, -4.39150654e-06f);
    p = fmaf(p, w, 0.00021858087f);
    p = fmaf(p, w, -0.00125372503f);
    p = fmaf(p, w, -0.00417768164f);
    p = fmaf(p, w, 0.246640727f);
    p = fmaf(p, w, 1.50140941f);
  } else {
    w = sqrtf(w) - 3.0f;
    p = -0.000200214257f;
    p = fmaf(p, w, 0.000100950558f);
    p = fmaf(p, w, 0.00134934322f);
    p = fmaf(p, w, -0.00367342844f);
    p = fmaf(p, w, 0.00573950773f);
    p = fmaf(p, w, -0.0076224613f);
    p = fmaf(p, w, 0.00943887047f);
    p = fmaf(p, w, 1.00167406f);
    p = fmaf(p, w, 2.83297682f);
  }
  return p * x;
}

__device__ inline float bits_to_normal(uint32_t bits) {
  uint32_t fb = (bits >> 9) | 0x3f800000u;
  float f = __uint_as_float(fb) - 1.0f;
  float u = f * 2.0f + (-0.99999994f);
  u = fmaxf(-0.99999994f, u);
  return 1.41421356f * erfinv_f(u);
}

// R_s: fp32 [1024][512] + split planes into XHh/XHl s-rows cols 0..511
__global__ __launch_bounds__(256) void rng_kernel(float* __restrict__ Rs,
                                                  u16* __restrict__ XHh,
                                                  u16* __restrict__ XHl,
                                                  uint32_t k0, uint32_t k1) {
  uint32_t i = blockIdx.x * 256 + threadIdx.x;   // 524288
  uint32_t o0, o1;
  tf2x32(k0, k1, 0u, i, o0, o1);
  float val = bits_to_normal(o0 ^ o1);
  uint32_t row = i >> 9, col = i & 511;
  Rs[row * 512 + col] = val;
  u16 h, lo;
  split2(val, h, lo);
  XHh[row * 1024 + col] = h;
  XHl[row * 1024 + col] = lo;
}

__global__ __launch_bounds__(256) void count_kernel(const int* __restrict__ ei_s,
                                                    const int* __restrict__ ei_t,
                                                    int* __restrict__ Acnt,
                                                    int* __restrict__ degd,
                                                    int* __restrict__ degs) {
  int e = blockIdx.x * 256 + threadIdx.x;        // 32768
  int side = e >> 14, idx = e & 16383;
  const int* ei = side ? ei_t : ei_s;
  int src = ei[idx], dst = ei[16384 + idx];
  int g = (dst >> 7) + side * 8;
  int dl = dst & 127, sl = src & 127;
  atomicAdd(&Acnt[(g * 128 + dl) * 128 + sl], 1);
  atomicAdd(&degd[g * 128 + dl], 1);
  atomicAdd(&degs[g * 128 + sl], 1);
}

__global__ __launch_bounds__(256) void norm_adj_kernel(const int* __restrict__ Acnt,
                                                       const int* __restrict__ degd,
                                                       const int* __restrict__ degs,
                                                       float* __restrict__ M1,
                                                       float* __restrict__ M2) {
  int idx = blockIdx.x * 256 + threadIdx.x;      // 16*128*128
  int g = idx >> 14, d = (idx >> 7) & 127, s = idx & 127;
  float a = (float)Acnt[idx];
  M1[idx] = a / (float)max(degd[g * 128 + d], 1);
  M2[(g * 128 + s) * 128 + d] = a / (float)max(degs[g * 128 + s], 1);
}

__global__ __launch_bounds__(256) void pack_kernel(const float* __restrict__ W1,
                                                   const float* __restrict__ W2,
                                                   const float* __restrict__ Wr,
                                                   float* __restrict__ Wcat) {
  int idx = blockIdx.x * 256 + threadIdx.x;      // 512 * 384 float4s
  int k = idx / 384, j4 = (idx % 384) * 4;
  float4 v;
  if (j4 < 512)       v = *(const float4*)&W1[k * 512 + j4];
  else if (j4 < 1024) v = *(const float4*)&W2[k * 512 + j4 - 512];
  else                v = *(const float4*)&Wr[k * 512 + j4 - 1024];
  *(float4*)&Wcat[k * 1536 + j4] = v;
}

// W [K][N] fp32 -> W^T hi/lo [N][K] bf16 (for MFMA B staging)
__global__ __launch_bounds__(256) void convert_wT(const float* __restrict__ W,
                                                  u16* __restrict__ Th,
                                                  u16* __restrict__ Tl,
                                                  int K, int N) {
  int id = blockIdx.x * 256 + threadIdx.x;
  int k = id / N, n = id - k * N;
  u16 h, lo;
  split2(W[id], h, lo);
  Th[n * K + k] = h;
  Tl[n * K + k] = lo;
}

// x_s/x_t -> XH split planes (left 512 cols)
__global__ __launch_bounds__(256) void copyx_kernel(const float* __restrict__ xs,
                                                    const float* __restrict__ xt,
                                                    u16* __restrict__ XHh,
                                                    u16* __restrict__ XHl) {
  int idx = blockIdx.x * 256 + threadIdx.x;      // 2048 rows * 128 float4s
  int row = idx >> 7, c4 = (idx & 127) << 2;
  const float* src = (row < 1024) ? (xs + row * 512 + c4)
                                  : (xt + (row - 1024) * 512 + c4);
  float4 v = *(const float4*)src;
  u16 h[4], lo[4];
  split2(v.x, h[0], lo[0]); split2(v.y, h[1], lo[1]);
  split2(v.z, h[2], lo[2]); split2(v.w, h[3], lo[3]);
  uint2 hv = {(u32)h[0] | ((u32)h[1] << 16), (u32)h[2] | ((u32)h[3] << 16)};
  uint2 lv = {(u32)lo[0] | ((u32)lo[1] << 16), (u32)lo[2] | ((u32)lo[3] << 16)};
  *(uint2*)&XHh[row * 1024 + c4] = hv;
  *(uint2*)&XHl[row * 1024 + c4] = lv;
}

// ---- split-bf16 MFMA GEMM: C[M][N] = (Ah+Al)[M][K] @ (Bh+Bl)^T[N][K] -------
// 64x64 tile, BK=64, 4 waves (2x2), per-wave 32x32 (2x2 16x16 frags).
// LDS rows are 128B, XOR-swizzled (chunk ^= row&7) -> conflict-free b128 reads.
__global__ __launch_bounds__(256) void mfma_gemm(
    int K, const u16* __restrict__ Ah, const u16* __restrict__ Al, int lda,
    const u16* __restrict__ Bh, const u16* __restrict__ Bl, int ldb,
    float* __restrict__ C, int ldc, const float* __restrict__ bias) {
  __shared__ u16 As[2][64][64];
  __shared__ u16 Bs[2][64][64];
  const int tid = threadIdx.x;
  const int m0 = blockIdx.y * 64, n0 = blockIdx.x * 64;
  const int l = tid & 63;
  const int w = tid >> 6;
  const int wr = (w >> 1) * 32, wc = (w & 1) * 32;
  const int l15 = l & 15, lq = l >> 4;
  f32x4 acc[2][2] = {};
  const int sr = tid >> 3, sc = tid & 7;
  for (int k0 = 0; k0 < K; k0 += 64) {
    __syncthreads();
#pragma unroll
    for (int p = 0; p < 2; ++p) {
      int r = sr + p * 32;
      int dst = (sc ^ (r & 7)) * 8;
      *(uint4*)&As[0][r][dst] = *(const uint4*)&Ah[(m0 + r) * lda + k0 + sc * 8];
      *(uint4*)&As[1][r][dst] = *(const uint4*)&Al[(m0 + r) * lda + k0 + sc * 8];
      *(uint4*)&Bs[0][r][dst] = *(const uint4*)&Bh[(n0 + r) * ldb + k0 + sc * 8];
      *(uint4*)&Bs[1][r][dst] = *(const uint4*)&Bl[(n0 + r) * ldb + k0 + sc * 8];
    }
    __syncthreads();
#pragma unroll
    for (int kk = 0; kk < 2; ++kk) {
      short8 aH[2], aL[2], bH[2], bL[2];
#pragma unroll
      for (int i = 0; i < 2; ++i) {
        int mr = wr + i * 16 + l15;
        int ca = ((kk * 4 + lq) ^ (mr & 7)) * 8;
        aH[i] = *(const short8*)&As[0][mr][ca];
        aL[i] = *(const short8*)&As[1][mr][ca];
        int nr = wc + i * 16 + l15;
        int cb = ((kk * 4 + lq) ^ (nr & 7)) * 8;
        bH[i] = *(const short8*)&Bs[0][nr][cb];
        bL[i] = *(const short8*)&Bs[1][nr][cb];
      }
#pragma unroll
      for (int i = 0; i < 2; ++i)
#pragma unroll
        for (int j = 0; j < 2; ++j) {
          acc[i][j] = __builtin_amdgcn_mfma_f32_16x16x32_bf16(aH[i], bH[j], acc[i][j], 0, 0, 0);
          acc[i][j] = __builtin_amdgcn_mfma_f32_16x16x32_bf16(aL[i], bH[j], acc[i][j], 0, 0, 0);
          acc[i][j] = __builtin_amdgcn_mfma_f32_16x16x32_bf16(aH[i], bL[j], acc[i][j], 0, 0, 0);
        }
    }
  }
#pragma unroll
  for (int i = 0; i < 2; ++i)
#pragma unroll
    for (int j = 0; j < 2; ++j) {
      int n = n0 + wc + j * 16 + l15;
      float bv = bias ? bias[n] : 0.f;
#pragma unroll
      for (int r = 0; r < 4; ++r) {
        int m = m0 + wr + i * 16 + lq * 4 + r;
        C[m * ldc + n] = acc[i][j][r] + bv;
      }
    }
}

// ---------------- generic fp32 tiled GEMM, 64x64x16, 256 thr, 4x4/thr -------
// optional split-bf16 secondary output (outh/outl, used by R_t)
template <int TRANSA, int TRANSB>
__global__ __launch_bounds__(256) void gemm_kernel(
    int M, int N, int K,
    const float* __restrict__ A, int lda, int strideA,
    const float* __restrict__ B, int ldb, int strideB,
    float* __restrict__ C, int ldc, int strideC,
    const float* __restrict__ bias, int beta,
    u16* __restrict__ outh, u16* __restrict__ outl, int ldo, int strideO) {
  int batch = blockIdx.z;
  A += (size_t)batch * strideA;
  B += (size_t)batch * strideB;
  C += (size_t)batch * strideC;
  int m0 = blockIdx.y * 64, n0 = blockIdx.x * 64;
  __shared__ float As[16][64];
  __shared__ float Bs[16][64];
  int tid = threadIdx.x;
  int tx = tid & 15, ty = tid >> 4;
  float acc[4][4] = {};
  for (int k0 = 0; k0 < K; k0 += 16) {
    if (!TRANSA) {
      int m_l = tid & 63, k_l = (tid >> 6) << 2;
      float4 av = *(const float4*)&A[(m0 + m_l) * lda + k0 + k_l];
      As[k_l + 0][m_l] = av.x; As[k_l + 1][m_l] = av.y;
      As[k_l + 2][m_l] = av.z; As[k_l + 3][m_l] = av.w;
    } else {  // A is KxM
      int k_l = tid >> 4, m_l = (tid & 15) << 2;
      float4 av = *(const float4*)&A[(k0 + k_l) * lda + m0 + m_l];
      *(float4*)&As[k_l][m_l] = av;
    }
    if (!TRANSB) {
      int k_l = tid >> 4, n_l = (tid & 15) << 2;
      float4 bv = *(const float4*)&B[(k0 + k_l) * ldb + n0 + n_l];
      *(float4*)&Bs[k_l][n_l] = bv;
    } else {  // B is NxK
      int n_l = tid >> 2, k_l = (tid & 3) << 2;
      float4 bv = *(const float4*)&B[(n0 + n_l) * ldb + k0 + k_l];
      Bs[k_l + 0][n_l] = bv.x; Bs[k_l + 1][n_l] = bv.y;
      Bs[k_l + 2][n_l] = bv.z; Bs[k_l + 3][n_l] = bv.w;
    }
    __syncthreads();
#pragma unroll
    for (int kk = 0; kk < 16; ++kk) {
      float4 a4 = *(const float4*)&As[kk][ty << 2];
      float4 b4 = *(const float4*)&Bs[kk][tx << 2];
      float av[4] = {a4.x, a4.y, a4.z, a4.w};
      float bv[4] = {b4.x, b4.y, b4.z, b4.w};
#pragma unroll
      for (int i = 0; i < 4; ++i)
#pragma unroll
        for (int j = 0; j < 4; ++j) acc[i][j] = fmaf(av[i], bv[j], acc[i][j]);
    }
    __syncthreads();
  }
#pragma unroll
  for (int i = 0; i < 4; ++i) {
    int m = m0 + (ty << 2) + i;
    float4* cp = (float4*)&C[m * ldc + n0 + (tx << 2)];
    float4 v = {acc[i][0], acc[i][1], acc[i][2], acc[i][3]};
    if (bias) {
      float4 bb = *(const float4*)&bias[n0 + (tx << 2)];
      v.x += bb.x; v.y += bb.y; v.z += bb.z; v.w += bb.w;
    }
    if (beta) {
      float4 c = *cp;
      v.x += c.x; v.y += c.y; v.z += c.z; v.w += c.w;
    }
    *cp = v;
    if (outh) {
      u16* oh = outh + (size_t)batch * strideO + m * ldo + n0 + (tx << 2);
      u16* ol = outl + (size_t)batch * strideO + m * ldo + n0 + (tx << 2);
      float vv[4] = {v.x, v.y, v.z, v.w};
#pragma unroll
      for (int c = 0; c < 4; ++c) {
        u16 h, lo;
        split2(vv[c], h, lo);
        oh[c] = h; ol[c] = lo;
      }
    }
  }
}

// relu + LayerNorm over 512 -> split h into XHh/XHl right half
__global__ __launch_bounds__(256) void relu_ln_kernel(
    const float* __restrict__ Y, const float* __restrict__ agg,
    const float* __restrict__ rb, const float* __restrict__ gam,
    const float* __restrict__ bet, u16* __restrict__ XHh,
    u16* __restrict__ XHl) {
  int row = blockIdx.x;
  int tid = threadIdx.x;
  int c0 = tid, c1 = tid + 256;
  float v0 = fmaxf(Y[row * 1536 + 1024 + c0] + rb[c0] + agg[row * 512 + c0], 0.f);
  float v1 = fmaxf(Y[row * 1536 + 1024 + c1] + rb[c1] + agg[row * 512 + c1], 0.f);
  float s = v0 + v1, s2 = v0 * v0 + v1 * v1;
#pragma unroll
  for (int off = 32; off > 0; off >>= 1) {
    s += __shfl_down(s, off);
    s2 += __shfl_down(s2, off);
  }
  __shared__ float red[2][4];
  int wid = tid >> 6, lane = tid & 63;
  if (lane == 0) { red[0][wid] = s; red[1][wid] = s2; }
  __syncthreads();
  s = red[0][0] + red[0][1] + red[0][2] + red[0][3];
  s2 = red[1][0] + red[1][1] + red[1][2] + red[1][3];
  float mu = s * (1.f / 512.f);
  float var = s2 * (1.f / 512.f) - mu * mu;
  float inv = 1.f / sqrtf(var + 1e-5f);
  float o0 = (v0 - mu) * inv * gam[c0] + bet[c0];
  float o1 = (v1 - mu) * inv * gam[c1] + bet[c1];
  u16 h, lo;
  split2(o0, h, lo);
  XHh[row * 1024 + 512 + c0] = h; XHl[row * 1024 + 512 + c0] = lo;
  split2(o1, h, lo);
  XHh[row * 1024 + 512 + c1] = h; XHl[row * 1024 + 512 + c1] = lo;
}

__global__ __launch_bounds__(64) void softmax_kernel(const float* __restrict__ SH,
                                                     float* __restrict__ S,
                                                     float* __restrict__ out2) {
  int row = blockIdx.x;      // 1024 = b*128+s
  int lane = threadIdx.x;    // 64
  float a = SH[row * 128 + lane];
  float b = SH[row * 128 + 64 + lane];
  float m = fmaxf(a, b);
#pragma unroll
  for (int off = 32; off > 0; off >>= 1) m = fmaxf(m, __shfl_xor(m, off));
  float e0 = expf(a - m), e1 = expf(b - m);
  float ssum = e0 + e1;
#pragma unroll
  for (int off = 32; off > 0; off >>= 1) ssum += __shfl_xor(ssum, off);
  float r0 = e0 / ssum, r1 = e1 / ssum;
  S[row * 128 + lane] = r0;
  S[row * 128 + 64 + lane] = r1;
  if (out2) {
    out2[row * 128 + lane] = r0;
    out2[row * 128 + 64 + lane] = r1;
  }
}

// S_hat[b,s,t] += sum_h relu(P_s[b,s,h] - P_t[b,t,h] + b1[h]) * w2[h] + b2
__global__ __launch_bounds__(128) void dist_kernel(const float* __restrict__ P,
                                                   const float* __restrict__ b1,
                                                   const float* __restrict__ w2,
                                                   const float* __restrict__ b2,
                                                   float* __restrict__ SH) {
  int bs = blockIdx.x;       // b*128+s
  int b = bs >> 7;
  int t = threadIdx.x;       // 128
  __shared__ float arow[128], w2s[128];
  arow[t] = P[bs * 128 + t] + b1[t];
  w2s[t] = w2[t];
  __syncthreads();
  const float* pt = &P[(1024 + b * 128 + t) * 128];
  float acc = 0.f;
#pragma unroll 8
  for (int h4 = 0; h4 < 128; h4 += 4) {
    float4 a = *(const float4*)&arow[h4];
    float4 w = *(const float4*)&w2s[h4];
    float4 p = *(const float4*)&pt[h4];
    acc += fmaxf(a.x - p.x, 0.f) * w.x + fmaxf(a.y - p.y, 0.f) * w.y +
           fmaxf(a.z - p.z, 0.f) * w.z + fmaxf(a.w - p.w, 0.f) * w.w;
  }
  SH[bs * 128 + t] += acc + b2[0];
}

// ---------------------------------------------------------------------------
extern "C" void kernel_launch(void* const* d_in, const int* in_sizes, int n_in,
                              void* d_out, int out_size, void* d_ws, size_t ws_size,
                              hipStream_t stream) {
  const float* x_s = (const float*)d_in[0];
  const int* ei_s = (const int*)d_in[1];
  const float* x_t = (const float*)d_in[4];
  const int* ei_t = (const int*)d_in[5];
  const float* e_lin1 = (const float*)d_in[8];
  const float* e_lin2 = (const float*)d_in[9];
  const float* e_rw = (const float*)d_in[10];
  const float* e_rb = (const float*)d_in[11];
  const float* e_g = (const float*)d_in[12];
  const float* e_b = (const float*)d_in[13];
  const float* e_fw = (const float*)d_in[14];
  const float* e_fb = (const float*)d_in[15];
  const float* c_lin1 = (const float*)d_in[16];
  const float* c_lin2 = (const float*)d_in[17];
  const float* c_rw = (const float*)d_in[18];
  const float* c_rb = (const float*)d_in[19];
  const float* c_g = (const float*)d_in[20];
  const float* c_b = (const float*)d_in[21];
  const float* c_fw = (const float*)d_in[22];
  const float* c_fb = (const float*)d_in[23];
  const float* m_w1 = (const float*)d_in[24];
  const float* m_b1 = (const float*)d_in[25];
  const float* m_w2 = (const float*)d_in[26];
  const float* m_b2 = (const float*)d_in[27];
  float* out = (float*)d_out;
  float* ws = (float*)d_ws;

  // workspace layout (float offsets); total 11800576 floats ~= 47.2 MB
  float* M1  = ws;                       // 262144  [16][128][128]
  float* M2  = ws + 262144;              // 262144
  float* Rs  = ws + 524288;              // 524288  [1024][512] fp32 R_s
  float* Y   = ws + 1048576;             // 3145728 [2048][1536] (also Wcat stage)
  float* AGG = ws + 4194304;             // 1048576 [2048][512]
  float* O   = ws + 5242880;             // 1048576 [2048][512] (also R_t fp32 dump)
  float* P   = ws + 6291456;             // 262144  [2048][128]
  float* SH  = ws + 6553600;             // 131072  [8][128][128]
  float* S   = ws + 6684672;             // 131072
  int* Acnt  = (int*)(ws + 6815744);     // 262144 ints
  int* degd  = (int*)(ws + 7077888);     // 2048
  int* degs  = (int*)(ws + 7079936);     // 2048
  u16* XHh   = (u16*)(ws + 7081984);     // [2048][1024] bf16 hi
  u16* XHl   = (u16*)(ws + 8130560);     // lo
  u16* WTeh  = (u16*)(ws + 9179136);     // WcatT_e [1536][512] hi
  u16* WTel  = (u16*)(ws + 9572352);
  u16* WTch  = (u16*)(ws + 9965568);
  u16* WTcl  = (u16*)(ws + 10358784);
  u16* FTeh  = (u16*)(ws + 10752000);    // FwT_e [512][1024] hi
  u16* FTel  = (u16*)(ws + 11014144);
  u16* FTch  = (u16*)(ws + 11276288);
  u16* FTcl  = (u16*)(ws + 11538432);

  hipMemsetAsync(Acnt, 0, (262144 + 2048 + 2048) * sizeof(int), stream);
  count_kernel<<<128, 256, 0, stream>>>(ei_s, ei_t, Acnt, degd, degs);
  norm_adj_kernel<<<1024, 256, 0, stream>>>(Acnt, degd, degs, M1, M2);
  // weights: pack Wcat into Y (staging), then transpose+split to bf16 planes
  pack_kernel<<<768, 256, 0, stream>>>(e_lin1, e_lin2, e_rw, Y);
  convert_wT<<<3072, 256, 0, stream>>>(Y, WTeh, WTel, 512, 1536);
  pack_kernel<<<768, 256, 0, stream>>>(c_lin1, c_lin2, c_rw, Y);
  convert_wT<<<3072, 256, 0, stream>>>(Y, WTch, WTcl, 512, 1536);
  convert_wT<<<2048, 256, 0, stream>>>(e_fw, FTeh, FTel, 1024, 512);
  convert_wT<<<2048, 256, 0, stream>>>(c_fw, FTch, FTcl, 1024, 512);
  copyx_kernel<<<1024, 256, 0, stream>>>(x_s, x_t, XHh, XHl);

  auto gnn = [&](const u16* WTh, const u16* WTl, const u16* FTh, const u16* FTl,
                 const float* rb, const float* g, const float* bb,
                 const float* Fb) {
    // Y = XH[:, :512] @ Wcat   (split-bf16 MFMA)
    mfma_gemm<<<dim3(24, 32, 1), 256, 0, stream>>>(
        512, XHh, XHl, 1024, WTh, WTl, 512, Y, 1536, nullptr);
    // agg = M1@Y1 ; agg += M2@Y2   (16 batched, fp32)
    gemm_kernel<0, 0><<<dim3(8, 2, 16), 256, 0, stream>>>(
        128, 512, 128, M1, 128, 16384, Y, 1536, 128 * 1536, AGG, 512, 128 * 512,
        nullptr, 0, nullptr, nullptr, 0, 0);
    gemm_kernel<0, 0><<<dim3(8, 2, 16), 256, 0, stream>>>(
        128, 512, 128, M2, 128, 16384, Y + 512, 1536, 128 * 1536, AGG, 512,
        128 * 512, nullptr, 1, nullptr, nullptr, 0, 0);
    relu_ln_kernel<<<2048, 256, 0, stream>>>(Y, AGG, rb, g, bb, XHh, XHl);
    // O = XH @ Fw + Fb   (split-bf16 MFMA)
    mfma_gemm<<<dim3(8, 32, 1), 256, 0, stream>>>(
        1024, XHh, XHl, 1024, FTh, FTl, 1024, O, 512, Fb);
  };

  // ---- embedding GNN -> O holds Hs (rows 0..1023), Ht (1024..2047)
  gnn(WTeh, WTel, FTeh, FTel, e_rb, e_g, e_b, e_fb);
  // S_hat[b] = Hs[b] @ Ht[b]^T   (8 batched, transB, fp32)
  gemm_kernel<0, 1><<<dim3(2, 2, 8), 256, 0, stream>>>(
      128, 128, 512, O, 512, 128 * 512, O + 1024 * 512, 512, 128 * 512, SH, 128,
      128 * 128, nullptr, 0, nullptr, nullptr, 0, 0);

  for (int t = 0; t < 10; ++t) {
    softmax_kernel<<<1024, 64, 0, stream>>>(SH, S, (t == 0) ? out : nullptr);
    uint32_t fk0, fk1;
    tf2x32(0u, 42u, 0u, (uint32_t)t, fk0, fk1);  // fold_in(key(42), t)
    rng_kernel<<<2048, 256, 0, stream>>>(Rs, XHh, XHl, fk0, fk1);
    // R_t[b] = S[b]^T @ R_s[b] -> split into XH t-rows left (fp32 dump in O)
    gemm_kernel<1, 0><<<dim3(8, 2, 8), 256, 0, stream>>>(
        128, 512, 128, S, 128, 128 * 128, Rs, 512, 128 * 512, O, 512, 128 * 512,
        nullptr, 0, XHh + 1024 * 1024, XHl + 1024 * 1024, 1024, 128 * 1024);
    gnn(WTch, WTcl, FTch, FTcl, c_rb, c_g, c_b, c_fb);
    // P = O @ m_w1 + m_b1  (fp32)
    gemm_kernel<0, 0><<<dim3(2, 32, 1), 256, 0, stream>>>(
        2048, 128, 512, O, 512, 0, m_w1, 128, 0, P, 128, 0, m_b1, 0,
        nullptr, nullptr, 0, 0);
    dist_kernel<<<1024, 128, 0, stream>>>(P, m_b1, m_w2, m_b2, SH);
  }
  softmax_kernel<<<1024, 64, 0, stream>>>(SH, S, out + 131072);
}